// Round 9
// baseline (339.409 us; speedup 1.0000x reference)
//
#include <hip/hip_runtime.h>
#include <hip/hip_fp16.h>
#include <stdint.h>

#define FP8_MAX_V 448.0f
#define BM 128
#define BN 128
#define BKB 128  // K-bytes per tile step (fp8 => 128 elements); LDS row = 128 B

typedef float floatx4 __attribute__((ext_vector_type(4)));
typedef int intx4 __attribute__((ext_vector_type(4)));
typedef int intx8 __attribute__((ext_vector_type(8)));

// asm wait/barrier with full compiler fencing (rule #18).
#define WAITVM(n)                                              \
  do {                                                         \
    asm volatile("s_waitcnt vmcnt(" #n ")" ::: "memory");      \
    __builtin_amdgcn_sched_barrier(0);                         \
  } while (0)
#define BARRIER()                                              \
  do {                                                         \
    __builtin_amdgcn_sched_barrier(0);                         \
    __builtin_amdgcn_s_barrier();                              \
    __builtin_amdgcn_sched_barrier(0);                         \
  } while (0)

// Deterministic bf16 round-to-nearest-even of an fp32 value, returned widened to fp32.
__device__ __forceinline__ float bf16_rne(float v) {
  uint32_t u = __float_as_uint(v);
  u = (u + 0x7fffu + ((u >> 16) & 1u)) & 0xffff0000u;
  return __uint_as_float(u);
}

// Pack 4 fp32 (already clipped to +-448) into 4 OCP e4m3fn bytes via HW RNE cvt.
__device__ __forceinline__ uint32_t pack4_fp8(float a, float b, float c, float d) {
  int p = 0;
  p = __builtin_amdgcn_cvt_pk_fp8_f32(a, b, p, false);  // bytes 0..1
  p = __builtin_amdgcn_cvt_pk_fp8_f32(c, d, p, true);   // bytes 2..3
  return (uint32_t)p;
}

__device__ __forceinline__ void gload_lds16(const uint8_t* g, uint8_t* l) {
  __builtin_amdgcn_global_load_lds(
      (const __attribute__((address_space(1))) uint32_t*)g,
      (__attribute__((address_space(3))) uint32_t*)l,
      16, 0, 0);
}

// Per-row quantization: amax over K -> scale -> fp8. FP16RT: fp16 round-trip the
// scale (weight path, matches reference's scale.astype(fp16).astype(fp32)).
template <bool FP16RT>
__global__ __launch_bounds__(256) void quant_rows_kernel(
    const float* __restrict__ in, uint8_t* __restrict__ out8,
    float* __restrict__ scales, int K) {
  const int row = blockIdx.x;
  const int tid = threadIdx.x;
  const float* rp = in + (size_t)row * K;

  // K = 4096: 16 floats/thread as 4x float4, coalesced (stride-256 float4s).
  float4 v[4];
  float amax = 0.f;
#pragma unroll
  for (int i = 0; i < 4; ++i) {
    v[i] = ((const float4*)rp)[i * 256 + tid];
    amax = fmaxf(amax, fmaxf(fmaxf(fabsf(v[i].x), fabsf(v[i].y)),
                             fmaxf(fabsf(v[i].z), fabsf(v[i].w))));
  }
#pragma unroll
  for (int off = 32; off; off >>= 1) amax = fmaxf(amax, __shfl_xor(amax, off));
  __shared__ float red[4];
  if ((tid & 63) == 0) red[tid >> 6] = amax;
  __syncthreads();
  amax = fmaxf(fmaxf(red[0], red[1]), fmaxf(red[2], red[3]));

  float scale = fmaxf(amax / FP8_MAX_V, 1e-6f);
  if (FP16RT) scale = __half2float(__float2half(scale));  // RNE, matches jnp fp16 round-trip
  if (tid == 0) scales[row] = scale;

  uint32_t* op = (uint32_t*)(out8 + (size_t)row * K);
#pragma unroll
  for (int i = 0; i < 4; ++i) {
    // true fp32 division (correctly rounded) to match numpy's x / scale
    float qa = fminf(fmaxf(v[i].x / scale, -FP8_MAX_V), FP8_MAX_V);
    float qb = fminf(fmaxf(v[i].y / scale, -FP8_MAX_V), FP8_MAX_V);
    float qc = fminf(fmaxf(v[i].z / scale, -FP8_MAX_V), FP8_MAX_V);
    float qd = fminf(fmaxf(v[i].w / scale, -FP8_MAX_V), FP8_MAX_V);
    op[i * 256 + tid] = pack4_fp8(qa, qb, qc, qd);
  }
}

// C[t,o] = sum_k A8[t,k]*B8[o,k]  (both K-major), scaled + bias + bf16 round.
// Round-7 shell (128x128 tile, 4 waves 2x2, 64x64 wave-tile, MX-scaled
// mfma_scale_f32_16x16x128_f8f6f4 with UNIT scales, counted-vmcnt pipeline,
// 2 blocks/CU) with the B operand moved OUT of LDS into registers:
//   - A: global_load_lds staged, 2 x 16 KB LDS double buffer (32 KB total).
//   - B: per-wave direct global->VGPR fragment loads, double-buffered
//     (b0/b1, static names per rule #20), issued one tile ahead at tile head.
// DS reads halve (8 b128/wave/tile, A only) -> DS floor ~41 us < MFMA floor
// ~59 us: kernel becomes MFMA-bound.
//
// vmcnt ledger (per wave, per tile s): head WAITVM(4) leaves only
// stageA(s+1)'s 4 gloads in flight; drains loadB(s) [8 ops, issued at head of
// s-1] and stageA(s) [issued end of s-2]. Body: loadB(s+1) at head (a full
// compute span of latency cover), stageA(s+2) after the tail barrier.
// Race-free: As[s&1] rewritten only after the barrier ending its reads.
//
// LDS swizzle (T2, rule #21 both-sides): 16B chunk c16 within each 128B row
// XOR'd with (row&7); linear LDS dest + pre-swizzled global source +
// swizzled read (fragment = chunks {2*hi, 2*hi+1} ^ (fr&7)).
__global__ __launch_bounds__(256, 2) void gemm_fp8_kernel(
    const uint8_t* __restrict__ A8, const uint8_t* __restrict__ B8,
    const float* __restrict__ asc, const float* __restrict__ wsc,
    const float* __restrict__ bias, float* __restrict__ out,
    int M, int N, int K) {
  __shared__ __align__(16) uint8_t As[2][BM * BKB];  // 2 x 16 KB

  const int tid = threadIdx.x;
  const int lane = tid & 63;
  const int wid = tid >> 6;
  const int wr = wid >> 1;  // 0..1
  const int wc = wid & 1;   // 0..1

  const int ntn = N / BN;
  const int bm = blockIdx.x / ntn;
  const int bn = blockIdx.x % ntn;

  floatx4 acc[4][4] = {};

  // A staging: thread tid -> LDS linear offset tid*16 (row=tid>>3, chunk=tid&7),
  // global source chunk = (tid&7) ^ (row&7). Row stride 32 between the 4 calls
  // preserves (row&7), so one source offset serves all calls.
  const int srow = tid >> 3;                      // 0..31
  const int sc_log = (tid & 7) ^ (srow & 7);      // pre-swizzled source chunk
  const uint8_t* ga0 = A8 + (size_t)(bm * BM + srow) * K + sc_log * 16;
  const size_t rstep = (size_t)32 * K;

  const int fr = lane & 15;        // fragment row/col within 16
  const int hi = lane >> 4;        // 0..3: K-block of 32 elems within the 128-tile
  const int fsw = fr & 7;          // read-side swizzle key
  // Lane's 32B LDS fragment = chunks {2*hi, 2*hi+1}, each XOR-swizzled.
  const int cls = ((2 * hi) ^ fsw) * 16;      // low 16B chunk byte offset
  const int chs = ((2 * hi + 1) ^ fsw) * 16;  // high 16B chunk byte offset

  // B direct-load base: lane (fr,hi) reads 32 contiguous bytes of row
  // bn*BN + wc*64 + n*16 + fr at K-offset t*BKB + hi*32 (two dwordx4).
  const uint8_t* gBb = B8 + (size_t)(bn * BN + wc * 64 + fr) * K + hi * 32;

  auto stageA = [&](int buf, int k0) {
    uint8_t* lA = As[buf] + tid * 16;
#pragma unroll
    for (int i = 0; i < 4; ++i) gload_lds16(ga0 + i * rstep + k0, lA + i * 4096);
  };

  auto loadB = [&](intx8* bb, int k0) {
#pragma unroll
    for (int n = 0; n < 4; ++n) {
      const uint8_t* p = gBb + (size_t)(n * 16) * K + k0;
      intx4 lo = *(const intx4*)p;
      intx4 hh = *(const intx4*)(p + 16);
      bb[n] = (intx8){lo.x, lo.y, lo.z, lo.w, hh.x, hh.y, hh.z, hh.w};
    }
  };

  auto computeA = [&](int buf, const intx8* bb) {
    const uint8_t* Ab = As[buf];
    intx8 a[4];
#pragma unroll
    for (int m = 0; m < 4; ++m) {
      const uint8_t* p = Ab + (size_t)(wr * 64 + m * 16 + fr) * BKB;
      intx4 lo = *(const intx4*)(p + cls);
      intx4 hh = *(const intx4*)(p + chs);
      a[m] = (intx8){lo.x, lo.y, lo.z, lo.w, hh.x, hh.y, hh.z, hh.w};
    }
#pragma unroll
    for (int m = 0; m < 4; ++m)
#pragma unroll
      for (int n = 0; n < 4; ++n)
        // cbsz=0 (A=fp8 e4m3), blgp=0 (B=fp8 e4m3), scales = e8m0 0x7F = 1.0
        acc[m][n] = __builtin_amdgcn_mfma_scale_f32_16x16x128_f8f6f4(
            a[m], bb[n], acc[m][n], 0, 0, 0, 0x7F7F7F7F, 0, 0x7F7F7F7F);
  };

  const int NT = K / BKB;  // 32 (even)
  intx8 b0[4], b1[4];
  stageA(0, 0);      // 4 ops
  loadB(b0, 0);      // 8 ops
  stageA(1, BKB);    // 4 ops  -> head of tile 0: WAITVM(4) leaves these 4

  for (int t = 0; t < NT; t += 2) {
    // ---- even tile t: compute As[0] x b0; load b1 <- B(t+1); stage A(t+2)
    if (t + 1 < NT) WAITVM(4); else WAITVM(0);
    BARRIER();
    if (t + 1 < NT) loadB(b1, (t + 1) * BKB);
    computeA(0, b0);
    BARRIER();
    if (t + 2 < NT) stageA(0, (t + 2) * BKB);

    // ---- odd tile t+1: compute As[1] x b1; load b0 <- B(t+2); stage A(t+3)
    if (t + 2 < NT) WAITVM(4); else WAITVM(0);
    BARRIER();
    if (t + 2 < NT) loadB(b0, (t + 2) * BKB);
    computeA(1, b1);
    BARRIER();
    if (t + 3 < NT) stageA(1, (t + 3) * BKB);
  }

  // Epilogue: C/D 16x16 layout col=lane&15, row=(lane>>4)*4+r (dtype-independent;
  // f8f6f4-scaled C/D layout is shape-determined per m121-m128).
  const int rbase = bm * BM + wr * 64;
  const int cbase = bn * BN + wc * 64;
#pragma unroll
  for (int n = 0; n < 4; ++n) {
    const int col = cbase + n * 16 + fr;
    const float wv = wsc[col];
    const float bb = bf16_rne(bias[col]);  // bias.astype(bf16).astype(f32)
#pragma unroll
    for (int m = 0; m < 4; ++m) {
      const int r0 = rbase + m * 16 + hi * 4;
#pragma unroll
      for (int r = 0; r < 4; ++r) {
        const int row = r0 + r;
        // reference order: (acc * act_scale) * w_scale + bias_bf16, then bf16 RNE
        float v = (acc[m][n][r] * asc[row]) * wv + bb;
        out[(size_t)row * N + col] = bf16_rne(v);
      }
    }
  }
}

extern "C" void kernel_launch(void* const* d_in, const int* in_sizes, int n_in,
                              void* d_out, int out_size, void* d_ws, size_t ws_size,
                              hipStream_t stream) {
  const float* x = (const float*)d_in[0];     // [B,S,K] f32
  const float* w = (const float*)d_in[1];     // [N,K] f32
  const float* bias = (const float*)d_in[2];  // [N] f32
  float* out = (float*)d_out;                 // [M,N] f32 (bf16-rounded values)

  const int N = in_sizes[2];             // 4096 (D_OUT)
  const int K = in_sizes[1] / N;         // 4096 (D_IN)
  const int M = in_sizes[0] / K;         // 8192 tokens

  uint8_t* x8 = (uint8_t*)d_ws;                    // M*K bytes
  uint8_t* w8 = x8 + (size_t)M * K;                // N*K bytes
  float* asc = (float*)(w8 + (size_t)N * K);       // M floats
  float* wsc = asc + M;                            // N floats
  (void)ws_size; (void)n_in; (void)out_size;

  quant_rows_kernel<false><<<M, 256, 0, stream>>>(x, x8, asc, K);
  quant_rows_kernel<true><<<N, 256, 0, stream>>>(w, w8, wsc, K);
  gemm_fp8_kernel<<<(M / BM) * (N / BN), 256, 0, stream>>>(x8, w8, asc, wsc, bias, out, M, N, K);
}

// Round 10
// 193.487 us; speedup vs baseline: 1.7542x; 1.7542x over previous
//
#include <hip/hip_runtime.h>
#include <hip/hip_fp16.h>
#include <stdint.h>

#define FP8_MAX_V 448.0f
#define BM 128
#define BN 128
#define BKB 128  // K-bytes per tile step (fp8 => 128 elements); LDS row = 128 B

typedef float floatx4 __attribute__((ext_vector_type(4)));
typedef int intx4 __attribute__((ext_vector_type(4)));
typedef int intx8 __attribute__((ext_vector_type(8)));

// asm wait/barrier with full compiler fencing (rule #18).
#define WAITVM(n)                                              \
  do {                                                         \
    asm volatile("s_waitcnt vmcnt(" #n ")" ::: "memory");      \
    __builtin_amdgcn_sched_barrier(0);                         \
  } while (0)
#define BARRIER()                                              \
  do {                                                         \
    __builtin_amdgcn_sched_barrier(0);                         \
    __builtin_amdgcn_s_barrier();                              \
    __builtin_amdgcn_sched_barrier(0);                         \
  } while (0)

// Deterministic bf16 round-to-nearest-even of an fp32 value, returned widened to fp32.
__device__ __forceinline__ float bf16_rne(float v) {
  uint32_t u = __float_as_uint(v);
  u = (u + 0x7fffu + ((u >> 16) & 1u)) & 0xffff0000u;
  return __uint_as_float(u);
}

// Pack 4 fp32 (already clipped to +-448) into 4 OCP e4m3fn bytes via HW RNE cvt.
__device__ __forceinline__ uint32_t pack4_fp8(float a, float b, float c, float d) {
  int p = 0;
  p = __builtin_amdgcn_cvt_pk_fp8_f32(a, b, p, false);  // bytes 0..1
  p = __builtin_amdgcn_cvt_pk_fp8_f32(c, d, p, true);   // bytes 2..3
  return (uint32_t)p;
}

__device__ __forceinline__ void gload_lds16(const uint8_t* g, uint8_t* l) {
  __builtin_amdgcn_global_load_lds(
      (const __attribute__((address_space(1))) uint32_t*)g,
      (__attribute__((address_space(3))) uint32_t*)l,
      16, 0, 0);
}

// Fused per-row quantization for BOTH x (blocks 0..M-1) and w (blocks M..M+N-1):
// amax over K -> scale -> fp8. Weight path fp16-round-trips the scale (matches
// reference's scale.astype(fp16).astype(fp32)). One launch instead of two.
__global__ __launch_bounds__(256) void quant_all_kernel(
    const float* __restrict__ x, const float* __restrict__ w,
    uint8_t* __restrict__ x8, uint8_t* __restrict__ w8,
    float* __restrict__ asc, float* __restrict__ wsc, int M, int K) {
  const int blk = blockIdx.x;
  const bool isW = blk >= M;
  const int row = isW ? (blk - M) : blk;
  const float* rp = (isW ? w : x) + (size_t)row * K;
  uint8_t* out8 = (isW ? w8 : x8) + (size_t)row * K;
  float* scp = (isW ? wsc : asc) + row;
  const int tid = threadIdx.x;

  // K = 4096: 16 floats/thread as 4x float4, coalesced (stride-256 float4s).
  float4 v[4];
  float amax = 0.f;
#pragma unroll
  for (int i = 0; i < 4; ++i) {
    v[i] = ((const float4*)rp)[i * 256 + tid];
    amax = fmaxf(amax, fmaxf(fmaxf(fabsf(v[i].x), fabsf(v[i].y)),
                             fmaxf(fabsf(v[i].z), fabsf(v[i].w))));
  }
#pragma unroll
  for (int off = 32; off; off >>= 1) amax = fmaxf(amax, __shfl_xor(amax, off));
  __shared__ float red[4];
  if ((tid & 63) == 0) red[tid >> 6] = amax;
  __syncthreads();
  amax = fmaxf(fmaxf(red[0], red[1]), fmaxf(red[2], red[3]));

  float scale = fmaxf(amax / FP8_MAX_V, 1e-6f);
  if (isW) scale = __half2float(__float2half(scale));  // RNE, matches jnp fp16 round-trip
  if (tid == 0) *scp = scale;

  uint32_t* op = (uint32_t*)out8;
#pragma unroll
  for (int i = 0; i < 4; ++i) {
    // true fp32 division (correctly rounded) to match numpy's x / scale
    float qa = fminf(fmaxf(v[i].x / scale, -FP8_MAX_V), FP8_MAX_V);
    float qb = fminf(fmaxf(v[i].y / scale, -FP8_MAX_V), FP8_MAX_V);
    float qc = fminf(fmaxf(v[i].z / scale, -FP8_MAX_V), FP8_MAX_V);
    float qd = fminf(fmaxf(v[i].w / scale, -FP8_MAX_V), FP8_MAX_V);
    op[i * 256 + tid] = pack4_fp8(qa, qb, qc, qd);
  }
}

// C[t,o] = sum_k A8[t,k]*B8[o,k]  (both K-major), scaled + bias + bf16 round.
// Round-7 proven shell: 128x128 tile, 4 waves 2x2, 64x64 wave-tile, MX-scaled
// mfma_scale_f32_16x16x128_f8f6f4 with UNIT scales (e8m0 0x7F = 1.0),
// counted-vmcnt pipeline, gload_lds staging, fr&7 16B-chunk XOR swizzle.
//
// This round: B SINGLE-buffered (A stays double-buffered) -> LDS 48 KB ->
// 3 blocks/CU = 12 waves/CU (+50% TLP vs r7's 2 blocks). B(t+1) is staged
// immediately after the tail barrier of tile t (all B reads done -> race-free)
// and lands by the head of t+1; its exposure is covered by the other two
// resident blocks.
//
// vmcnt ledger (per wave): tail of tile t issues B(t+1) [4] then A(t+2) [4].
// Steady in-flight at head of tile t: {A(t), B(t), A(t+1)} = 12 ops ->
// WAITVM(4) drains exactly A(t)+B(t) (the 8 oldest), keeps A(t+1) in flight.
// Prologue: stageA(0), stageB(0), stageA(1) = 12 in flight.
// Race-free: As[t&1] rewritten only after the barrier ending its reads; Bs
// rewritten only after the tail barrier; reads gated by all-waves WAITVM +
// head barrier.
__global__ __launch_bounds__(256, 2) void gemm_fp8_kernel(
    const uint8_t* __restrict__ A8, const uint8_t* __restrict__ B8,
    const float* __restrict__ asc, const float* __restrict__ wsc,
    const float* __restrict__ bias, float* __restrict__ out,
    int M, int N, int K) {
  __shared__ __align__(16) uint8_t As[2][BM * BKB];  // 2 x 16 KB
  __shared__ __align__(16) uint8_t Bs[BN * BKB];     // 1 x 16 KB

  const int tid = threadIdx.x;
  const int lane = tid & 63;
  const int wid = tid >> 6;
  const int wr = wid >> 1;  // 0..1
  const int wc = wid & 1;   // 0..1

  const int ntn = N / BN;
  const int bm = blockIdx.x / ntn;
  const int bn = blockIdx.x % ntn;

  floatx4 acc[4][4] = {};

  // Staging: thread tid -> LDS linear offset tid*16 (row=tid>>3, c16_phys=tid&7),
  // global source chunk = c16_phys ^ (row&7). Row stride 32 between the 4 calls
  // preserves (row&7), so one source offset serves all calls.
  const int srow = tid >> 3;                      // 0..31
  const int sc_log = (tid & 7) ^ (srow & 7);      // pre-swizzled source chunk
  const uint8_t* ga0 = A8 + (size_t)(bm * BM + srow) * K + sc_log * 16;
  const uint8_t* gb0 = B8 + (size_t)(bn * BN + srow) * K + sc_log * 16;
  const size_t rstep = (size_t)32 * K;

  const int fr = lane & 15;        // fragment row/col within 16
  const int hi = lane >> 4;        // 0..3: K-block of 32 elems within the 128-tile
  const int fsw = fr & 7;          // read-side swizzle key
  // Lane's 32B fragment = chunks {2*hi, 2*hi+1}, each XOR-swizzled.
  const int cls = ((2 * hi) ^ fsw) * 16;      // low 16B chunk byte offset
  const int chs = ((2 * hi + 1) ^ fsw) * 16;  // high 16B chunk byte offset

  auto stageA = [&](int buf, int k0) {
    uint8_t* lA = As[buf] + tid * 16;
#pragma unroll
    for (int i = 0; i < 4; ++i) gload_lds16(ga0 + i * rstep + k0, lA + i * 4096);
  };
  auto stageB = [&](int k0) {
    uint8_t* lB = Bs + tid * 16;
#pragma unroll
    for (int i = 0; i < 4; ++i) gload_lds16(gb0 + i * rstep + k0, lB + i * 4096);
  };

  auto compute = [&](int buf) {
    const uint8_t* Ab = As[buf];
    intx8 a[4], b[4];
#pragma unroll
    for (int m = 0; m < 4; ++m) {
      const uint8_t* p = Ab + (size_t)(wr * 64 + m * 16 + fr) * BKB;
      intx4 lo = *(const intx4*)(p + cls);
      intx4 hh = *(const intx4*)(p + chs);
      a[m] = (intx8){lo.x, lo.y, lo.z, lo.w, hh.x, hh.y, hh.z, hh.w};
    }
#pragma unroll
    for (int n = 0; n < 4; ++n) {
      const uint8_t* p = Bs + (size_t)(wc * 64 + n * 16 + fr) * BKB;
      intx4 lo = *(const intx4*)(p + cls);
      intx4 hh = *(const intx4*)(p + chs);
      b[n] = (intx8){lo.x, lo.y, lo.z, lo.w, hh.x, hh.y, hh.z, hh.w};
    }
#pragma unroll
    for (int m = 0; m < 4; ++m)
#pragma unroll
      for (int n = 0; n < 4; ++n)
        // cbsz=0 (A=fp8 e4m3), blgp=0 (B=fp8 e4m3), scales = e8m0 0x7F = 1.0
        acc[m][n] = __builtin_amdgcn_mfma_scale_f32_16x16x128_f8f6f4(
            a[m], b[n], acc[m][n], 0, 0, 0, 0x7F7F7F7F, 0, 0x7F7F7F7F);
  };

  const int NT = K / BKB;  // 32
  stageA(0, 0);
  stageB(0);
  stageA(1, BKB);  // in-flight: A(0), B(0), A(1) = 12

  for (int t = 0; t < NT; ++t) {
    // Drain A(t)+B(t) (the 8 oldest); keep A(t+1)'s 4 in flight.
    if (t + 1 < NT) WAITVM(4); else WAITVM(0);
    BARRIER();   // all waves' tile-t data resident; Bs free of writers
    compute(t & 1);
    BARRIER();   // all waves done reading As[t&1] and Bs
    if (t + 1 < NT) stageB((t + 1) * BKB);           // oldest outstanding first
    if (t + 2 < NT) stageA(t & 1, (t + 2) * BKB);    // refill freed A buffer
  }

  // Epilogue: C/D 16x16 layout col=lane&15, row=(lane>>4)*4+r (dtype-independent;
  // f8f6f4-scaled C/D layout is shape-determined per m121-m128).
  const int rbase = bm * BM + wr * 64;
  const int cbase = bn * BN + wc * 64;
#pragma unroll
  for (int n = 0; n < 4; ++n) {
    const int col = cbase + n * 16 + fr;
    const float wv = wsc[col];
    const float bb = bf16_rne(bias[col]);  // bias.astype(bf16).astype(f32)
#pragma unroll
    for (int m = 0; m < 4; ++m) {
      const int r0 = rbase + m * 16 + hi * 4;
#pragma unroll
      for (int r = 0; r < 4; ++r) {
        const int row = r0 + r;
        // reference order: (acc * act_scale) * w_scale + bias_bf16, then bf16 RNE
        float v = (acc[m][n][r] * asc[row]) * wv + bb;
        out[(size_t)row * N + col] = bf16_rne(v);
      }
    }
  }
}

extern "C" void kernel_launch(void* const* d_in, const int* in_sizes, int n_in,
                              void* d_out, int out_size, void* d_ws, size_t ws_size,
                              hipStream_t stream) {
  const float* x = (const float*)d_in[0];     // [B,S,K] f32
  const float* w = (const float*)d_in[1];     // [N,K] f32
  const float* bias = (const float*)d_in[2];  // [N] f32
  float* out = (float*)d_out;                 // [M,N] f32 (bf16-rounded values)

  const int N = in_sizes[2];             // 4096 (D_OUT)
  const int K = in_sizes[1] / N;         // 4096 (D_IN)
  const int M = in_sizes[0] / K;         // 8192 tokens

  uint8_t* x8 = (uint8_t*)d_ws;                    // M*K bytes
  uint8_t* w8 = x8 + (size_t)M * K;                // N*K bytes
  float* asc = (float*)(w8 + (size_t)N * K);       // M floats
  float* wsc = asc + M;                            // N floats
  (void)ws_size; (void)n_in; (void)out_size;

  quant_all_kernel<<<M + N, 256, 0, stream>>>(x, w, x8, w8, asc, wsc, M, K);
  gemm_fp8_kernel<<<(M / BM) * (N / BN), 256, 0, stream>>>(x8, w8, asc, wsc, bias, out, M, N, K);
}